// Round 19
// baseline (162.893 us; speedup 1.0000x reference)
//
#include <hip/hip_runtime.h>
#include <stdint.h>

#define S_LEN 2048
#define BATCH 2
#define EMB   1024
#define NHEAD 16
#define HDIM  64

typedef __bf16 bf8   __attribute__((ext_vector_type(8)));
typedef float  f32x4 __attribute__((ext_vector_type(4)));
typedef float  f32x16 __attribute__((ext_vector_type(16)));

__device__ __forceinline__ unsigned short f2bf(float f) {
    unsigned u = __builtin_bit_cast(unsigned, f);
    u += 0x7fffu + ((u >> 16) & 1u);          // round-to-nearest-even
    return (unsigned short)(u >> 16);
}
__device__ __forceinline__ float bf2f(unsigned short h) {
    unsigned u = ((unsigned)h) << 16;
    return __builtin_bit_cast(float, u);
}
__device__ __forceinline__ float fexp2(float x) { return __builtin_amdgcn_exp2f(x); }
__device__ __forceinline__ float f3max(float a, float b, float c) { return fmaxf(fmaxf(a, b), c); }

__device__ __forceinline__ void gl_lds16(const unsigned short* g, unsigned short* l) {
    __builtin_amdgcn_global_load_lds(
        (__attribute__((address_space(1))) void*)(void*)g,
        (__attribute__((address_space(3))) void*)(void*)l, 16, 0, 0);
}

// ---------------- fused prologue: rope tables + x cast + 4 weight casts ----------------
__global__ void k_prep(const float* __restrict__ x,
                       const float* __restrict__ w0, const float* __restrict__ w1,
                       const float* __restrict__ w2, const float* __restrict__ w3,
                       float* __restrict__ cosT, float* __restrict__ sinT,
                       unsigned short* __restrict__ xb,
                       unsigned short* __restrict__ o0, unsigned short* __restrict__ o1,
                       unsigned short* __restrict__ o2, unsigned short* __restrict__ o3)
{
    int bid = blockIdx.x;
    if (bid < 512) {
        int idx = bid * 256 + threadIdx.x;      // 2048*64 = 131072
        int s = idx >> 6, d = idx & 63, j = d & 31;
        float inv = exp2f(-13.28771237954945f * ((float)j * (1.0f / 32.0f)));
        float ang = (float)s * inv;
        cosT[idx] = cosf(ang);
        sinT[idx] = sinf(ang);
    } else if (bid < 4608) {
        int id = (bid - 512) * 256 + threadIdx.x;   // 1048576
        int b = id >> 19, rem = id & 524287;
        int s = rem >> 8, e4 = (rem & 255) << 2;
        float4 v = *(const float4*)&x[((size_t)(s * BATCH + b)) * EMB + e4];
        ushort4 o;
        o.x = f2bf(v.x); o.y = f2bf(v.y); o.z = f2bf(v.z); o.w = f2bf(v.w);
        *(ushort4*)&xb[((size_t)(b * S_LEN + s)) * EMB + e4] = o;
    } else {
        int id = (bid - 4608) * 256 + threadIdx.x;  // 1048576
        int seg = id >> 18, r = id & 262143;
        const float* s = seg == 0 ? w0 : seg == 1 ? w1 : seg == 2 ? w2 : w3;
        unsigned short* o = seg == 0 ? o0 : seg == 1 ? o1 : seg == 2 ? o2 : o3;
        float4 v = *(const float4*)&s[(size_t)r * 4];
        ushort4 u;
        u.x = f2bf(v.x); u.y = f2bf(v.y); u.z = f2bf(v.z); u.w = f2bf(v.w);
        *(ushort4*)&o[(size_t)r * 4] = u;
    }
}

// ---------------- merged QKV GEMM, BK=64 + XOR-swizzled LDS, rope fused ----------------
// Staging law: linear dest c=(row<<3)|slot; SOURCE col = (slot^(row&7))*8 (both-sides XOR).
// Read: As[row*64 + ((s)^(l15&7))*8], s = kk*4+lh  -> 2-way bank conflict (~free).
__global__ void __launch_bounds__(256) k_gemmQKV(
    const unsigned short* __restrict__ A,
    const unsigned short* __restrict__ Wq, const unsigned short* __restrict__ Wk,
    const unsigned short* __restrict__ Wv,
    const float* __restrict__ bqp, const float* __restrict__ bkp, const float* __restrict__ bvp,
    unsigned short* __restrict__ qout, unsigned short* __restrict__ kout,
    unsigned short* __restrict__ vout,
    const float* __restrict__ cosT, const float* __restrict__ sinT)
{
    __shared__ __align__(16) unsigned short Sh[16384];   // As[0,8192) Bs[8192,16384); V-transpose reuses [0,8704)
    unsigned short* As = Sh;
    unsigned short* Bs = Sh + 8192;
    const int z = blockIdx.z;
    const unsigned short* B = z == 0 ? Wq : z == 1 ? Wk : Wv;
    const float* bias = z == 0 ? bqp : z == 1 ? bkp : bvp;
    const int tid  = threadIdx.x;
    const int lane = tid & 63;
    const int wid  = tid >> 6;
    const int wm = wid >> 1, wn = wid & 1;
    const int l15 = lane & 15, lh = lane >> 4;
    const int mz = l15 & 7;
    const int tm0 = blockIdx.y * 128, tn0 = blockIdx.x * 128;
    const int K = 1024;

    f32x4 acc[4][4] = {};

    for (int k0 = 0; k0 < K; k0 += 64) {
        __syncthreads();
#pragma unroll
        for (int rnd = 0; rnd < 4; ++rnd) {
            int cbase = wid * 64 + rnd * 256;          // wave-uniform chunk base
            int c = cbase + lane;
            int row = c >> 3, ps = (c & 7) ^ (row & 7);
            gl_lds16(A + (size_t)(tm0 + row) * K + k0 + ps * 8, &As[cbase * 8]);
            gl_lds16(B + (size_t)(tn0 + row) * K + k0 + ps * 8, &Bs[cbase * 8]);
        }
        __syncthreads();
#pragma unroll
        for (int kk = 0; kk < 2; ++kk) {
            bf8 a[4], b[4];
#pragma unroll
            for (int i = 0; i < 4; ++i) {
                int s = kk * 4 + lh;
                a[i] = *(const bf8*)&As[(wm * 64 + i * 16 + l15) * 64 + (s ^ mz) * 8];
                b[i] = *(const bf8*)&Bs[(wn * 64 + i * 16 + l15) * 64 + (s ^ mz) * 8];
            }
#pragma unroll
            for (int i = 0; i < 4; ++i)
#pragma unroll
                for (int j = 0; j < 4; ++j)
                    acc[i][j] = __builtin_amdgcn_mfma_f32_16x16x32_bf16(a[i], b[j], acc[i][j], 0, 0, 0);
        }
    }

    if (z < 2) {
        unsigned short* C = z ? kout : qout;
        const float f = z ? 1.0f : 0.125f * 1.44269504089f;
#pragma unroll
        for (int i = 0; i < 4; ++i) {
            const int rowb = tm0 + wm * 64 + i * 16 + lh * 4;
#pragma unroll
            for (int j = 0; j < 2; ++j) {
                const int col = tn0 + wn * 64 + j * 16 + l15;   // d = j*16+l15 in [0,32)
                const int d = j * 16 + l15;
#pragma unroll
                for (int r = 0; r < 4; ++r) {
                    int m = rowb + r;
                    int sq = m & (S_LEN - 1);
                    float x1 = acc[i][j][r]     + bias[col];
                    float x2 = acc[i][j + 2][r] + bias[col + 32];
                    float c  = cosT[sq * 64 + d] * f;
                    float sn = sinT[sq * 64 + d] * f;
                    C[(size_t)m * EMB + col]      = f2bf(x1 * c - x2 * sn);
                    C[(size_t)m * EMB + col + 32] = f2bf(x2 * c + x1 * sn);
                }
            }
        }
    } else {
        // V: two m-half passes through an LDS [128 f][68] transpose tile,
        // then fully-coalesced 16B stores (8 lanes x 16B = 128B contiguous).
        __syncthreads();                 // all waves done with As/Bs
#pragma unroll
        for (int p = 0; p < 2; ++p) {
            if (wm == p) {
#pragma unroll
                for (int i = 0; i < 4; ++i) {
                    const int mloc = i * 16 + lh * 4;           // 0..63 within half
#pragma unroll
                    for (int j = 0; j < 4; ++j) {
                        const int fcol = wn * 64 + j * 16 + l15;
                        float bv = bias[tn0 + fcol];
#pragma unroll
                        for (int r = 0; r < 4; ++r)
                            Sh[fcol * 68 + mloc + r] = f2bf(acc[i][j][r] + bv);
                    }
                }
            }
            __syncthreads();
#pragma unroll
            for (int g = 0; g < 4; ++g) {
                int fcol = g * 32 + (tid >> 3);
                int mo = (tid & 7) * 8;
                *(uint4*)&vout[(size_t)(tn0 + fcol) * 4096 + tm0 + p * 64 + mo] =
                    *(const uint4*)&Sh[fcol * 68 + mo];
            }
            __syncthreads();
        }
    }
}

// ---------------- flash attention v17: deferred PV, race-fixed ----------------
__global__ void __launch_bounds__(256) k_attn11(
    const unsigned short* __restrict__ qb,
    const unsigned short* __restrict__ kb,
    const unsigned short* __restrict__ vT,
    unsigned short* __restrict__ ob)
{
    // Sm shorts: K(buf) at buf*4096, V(buf) at 12288 + buf*4096  (bytes: *2)
    __shared__ __align__(16) unsigned short Sm[24576];
    __shared__ float bl[4][32];
    const int tid = threadIdx.x, lane = tid & 63, wid = tid >> 6;
    const int l31 = lane & 31, hi = lane >> 5;
    const int bh = blockIdx.y;
    const int b = bh >> 4, h = bh & 15;
    const int q0 = blockIdx.x * 128 + wid * 32;

    const unsigned short* qrow = qb + ((size_t)(b * S_LEN + q0 + l31)) * EMB + h * HDIM + hi * 8;
    bf8 qf[4];
#pragma unroll
    for (int c = 0; c < 4; ++c) qf[c] = *(const bf8*)(qrow + c * 16);

    // ---- hoisted ds-read per-lane byte offsets (chunk A rows; B = +4096 imm) ----
    const int mz = l31 & 7;
    const int koA0 = l31 * 128 + (((0 * 2 + hi) ^ mz) << 4);
    const int koA1 = l31 * 128 + (((1 * 2 + hi) ^ mz) << 4);
    const int koA2 = l31 * 128 + (((2 * 2 + hi) ^ mz) << 4);
    const int koA3 = l31 * 128 + (((3 * 2 + hi) ^ mz) << 4);
    const char* ldsc = (const char*)Sm;

    // ---- hoisted stage per-lane byte offsets ----
    const int srow = lane >> 3, sp = lane & 7;
    const int r0 = wid * 16 + srow,     p0s = sp ^ (r0 & 7);
    const int r1 = wid * 16 + 8 + srow, p1s = sp ^ (r1 & 7);
    const int kgo0 = (r0 * EMB + p0s * 8) * 2, kgo1 = (r1 * EMB + p1s * 8) * 2;
    const int vgo0 = (r0 * (S_LEN * BATCH) + p0s * 8) * 2, vgo1 = (r1 * (S_LEN * BATCH) + p1s * 8) * 2;

    const unsigned short* kS = kb + ((size_t)(b * S_LEN)) * EMB + h * HDIM;
    const unsigned short* vS = vT + ((size_t)h * HDIM) * (S_LEN * BATCH) + b * S_LEN;

#define STAGE8(DBUF) do { \
    gl_lds16((const unsigned short*)((const char*)kS + kgo0), Sm + (DBUF) * 4096 + wid * 1024); \
    gl_lds16((const unsigned short*)((const char*)vS + vgo0), Sm + 12288 + (DBUF) * 4096 + wid * 1024); \
    gl_lds16((const unsigned short*)((const char*)kS + kgo1), Sm + (DBUF) * 4096 + wid * 1024 + 512); \
    gl_lds16((const unsigned short*)((const char*)vS + vgo1), Sm + 12288 + (DBUF) * 4096 + wid * 1024 + 512); \
    kS += 64 * EMB; vS += 64; } while (0)

    auto pack2 = [](float lo, float hh) -> unsigned {
        unsigned short a  = __builtin_bit_cast(unsigned short, (__bf16)lo);
        unsigned short bb = __builtin_bit_cast(unsigned short, (__bf16)hh);
        return ((unsigned)bb << 16) | a;
    };

    float m_run = 0.f, l_run = 0.f;
    f32x16 oacc0 = {}, oacc1 = {};
    const f32x16 Z16 = {};

    // persistent cross-iteration fragments (previous chunk's P and V)
    bf8 P0 = {}, P1 = {}, P2 = {}, P3 = {};
    bf8 Va0 = {}, Va1 = {}, Va2 = {}, Va3 = {};
    bf8 Vb0 = {}, Vb1 = {}, Vb2 = {}, Vb3 = {};

    STAGE8(0);
    STAGE8(1);

#define ABODY(BUF, DOSTG, LASTW, DOPV) do { \
    if (LASTW) asm volatile("s_waitcnt vmcnt(0)" ::: "memory"); \
    else       asm volatile("s_waitcnt vmcnt(4)" ::: "memory"); \
    __builtin_amdgcn_s_barrier(); \
    if (DOSTG) STAGE8(((BUF) + 2) % 3); \
    bf8 ka0 = *(const bf8*)(ldsc + koA0 + (BUF) * 8192); \
    bf8 ka1 = *(const bf8*)(ldsc + koA1 + (BUF) * 8192); \
    bf8 ka2 = *(const bf8*)(ldsc + koA2 + (BUF) * 8192); \
    bf8 ka3 = *(const bf8*)(ldsc + koA3 + (BUF) * 8192); \
    bf8 kb0 = *(const bf8*)(ldsc + koA0 + (BUF) * 8192 + 4096); \
    bf8 kb1 = *(const bf8*)(ldsc + koA1 + (BUF) * 8192 + 4096); \
    bf8 kb2 = *(const bf8*)(ldsc + koA2 + (BUF) * 8192 + 4096); \
    bf8 kb3 = *(const bf8*)(ldsc + koA3 + (BUF) * 8192 + 4096); \
    bf8 nva0 = *(const bf8*)(ldsc + koA0 + 24576 + (BUF) * 8192); \
    bf8 nva1 = *(const bf8*)(ldsc + koA1 + 24576 + (BUF) * 8192); \
    bf8 nva2 = *(const bf8*)(ldsc + koA2 + 24576 + (BUF) * 8192); \
    bf8 nva3 = *(const bf8*)(ldsc + koA3 + 24576 + (BUF) * 8192); \
    bf8 nvb0 = *(const bf8*)(ldsc + koA0 + 24576 + (BUF) * 8192 + 4096); \
    bf8 nvb1 = *(const bf8*)(ldsc + koA1 + 24576 + (BUF) * 8192 + 4096); \
    bf8 nvb2 = *(const bf8*)(ldsc + koA2 + 24576 + (BUF) * 8192 + 4096); \
    bf8 nvb3 = *(const bf8*)(ldsc + koA3 + 24576 + (BUF) * 8192 + 4096); \
    __builtin_amdgcn_s_setprio(1); \
    f32x16 stA = __builtin_amdgcn_mfma_f32_32x32x16_bf16(ka0, qf[0], Z16, 0, 0, 0); \
    f32x16 stB = __builtin_amdgcn_mfma_f32_32x32x16_bf16(kb0, qf[0], Z16, 0, 0, 0); \
    stA = __builtin_amdgcn_mfma_f32_32x32x16_bf16(ka1, qf[1], stA, 0, 0, 0); \
    stB = __builtin_amdgcn_mfma_f32_32x32x16_bf16(kb1, qf[1], stB, 0, 0, 0); \
    stA = __builtin_amdgcn_mfma_f32_32x32x16_bf16(ka2, qf[2], stA, 0, 0, 0); \
    stB = __builtin_amdgcn_mfma_f32_32x32x16_bf16(kb2, qf[2], stB, 0, 0, 0); \
    stA = __builtin_amdgcn_mfma_f32_32x32x16_bf16(ka3, qf[3], stA, 0, 0, 0); \
    stB = __builtin_amdgcn_mfma_f32_32x32x16_bf16(kb3, qf[3], stB, 0, 0, 0); \
    if (DOPV) { \
        oacc0 = __builtin_amdgcn_mfma_f32_32x32x16_bf16(P0, Va0, oacc0, 0, 0, 0); \
        oacc1 = __builtin_amdgcn_mfma_f32_32x32x16_bf16(P0, Vb0, oacc1, 0, 0, 0); \
        oacc0 = __builtin_amdgcn_mfma_f32_32x32x16_bf16(P1, Va1, oacc0, 0, 0, 0); \
        oacc1 = __builtin_amdgcn_mfma_f32_32x32x16_bf16(P1, Vb1, oacc1, 0, 0, 0); \
        oacc0 = __builtin_amdgcn_mfma_f32_32x32x16_bf16(P2, Va2, oacc0, 0, 0, 0); \
        oacc1 = __builtin_amdgcn_mfma_f32_32x32x16_bf16(P2, Vb2, oacc1, 0, 0, 0); \
        oacc0 = __builtin_amdgcn_mfma_f32_32x32x16_bf16(P3, Va3, oacc0, 0, 0, 0); \
        oacc1 = __builtin_amdgcn_mfma_f32_32x32x16_bf16(P3, Vb3, oacc1, 0, 0, 0); \
    } \
    __builtin_amdgcn_s_setprio(0); \
    float g0 = f3max(f3max(stA[0], stA[1], stA[2]),  f3max(stA[3], stA[4], stA[5]),  f3max(stA[6], stA[7], stA[8])); \
    float g1 = f3max(f3max(stA[9], stA[10], stA[11]), f3max(stA[12], stA[13], stA[14]), fmaxf(stA[15], stB[0])); \
    float g2 = f3max(f3max(stB[1], stB[2], stB[3]),  f3max(stB[4], stB[5], stB[6]),  f3max(stB[7], stB[8], stB[9])); \
    float g3 = f3max(f3max(stB[10], stB[11], stB[12]), f3max(stB[13], stB[14], stB[15]), fmaxf(g0, g1)); \
    float pmax = f3max(g2, g3, g0); \
    pmax = fmaxf(pmax, __shfl_xor(pmax, 32)); \
    if (!__all(pmax - m_run <= 11.54f)) { \
        float mnew = fmaxf(m_run, pmax); \
        float corr = fexp2(m_run - mnew); \
        l_run *= corr; m_run = mnew; \
        if (hi == 0) bl[wid][l31] = corr; \
        asm volatile("s_waitcnt lgkmcnt(0)" ::: "memory"); \
        _Pragma("unroll") for (int r = 0; r < 16; ++r) { \
            float c2 = bl[wid][(r & 3) + 8 * (r >> 2) + 4 * hi]; \
            oacc0[r] *= c2; oacc1[r] *= c2; } \
    } \
    float pA[16], pB[16]; \
    _Pragma("unroll") for (int r = 0; r < 16; ++r) pA[r] = fexp2(stA[r] - m_run); \
    _Pragma("unroll") for (int r = 0; r < 16; ++r) pB[r] = fexp2(stB[r] - m_run); \
    float sA = (((pA[0] + pA[1]) + (pA[2] + pA[3])) + ((pA[4] + pA[5]) + (pA[6] + pA[7]))) \
             + (((pA[8] + pA[9]) + (pA[10] + pA[11])) + ((pA[12] + pA[13]) + (pA[14] + pA[15]))); \
    float sB = (((pB[0] + pB[1]) + (pB[2] + pB[3])) + ((pB[4] + pB[5]) + (pB[6] + pB[7]))) \
             + (((pB[8] + pB[9]) + (pB[10] + pB[11])) + ((pB[12] + pB[13]) + (pB[14] + pB[15]))); \
    float psum = sA + sB; \
    psum += __shfl_xor(psum, 32); \
    l_run += psum; \
    unsigned a0w = pack2(pA[0], pA[1]),  a1w = pack2(pA[2], pA[3]); \
    unsigned a2w = pack2(pA[4], pA[5]),  a3w = pack2(pA[6], pA[7]); \
    unsigned a4w = pack2(pA[8], pA[9]),  a5w = pack2(pA[10], pA[11]); \
    unsigned a6w = pack2(pA[12], pA[13]), a7w = pack2(pA[14], pA[15]); \
    unsigned rA_ = (unsigned)__shfl_xor((int)(hi ? a0w : a2w), 32); \
    unsigned rB_ = (unsigned)__shfl_xor((int)(hi ? a1w : a3w), 32); \
    unsigned rC_ = (unsigned)__shfl_xor((int)(hi ? a4w : a6w), 32); \
    unsigned rD_ = (unsigned)__shfl_xor((int)(hi ? a5w : a7w), 32); \
    uint4 uA0 = hi ? uint4{rA_, rB_, a2w, a3w} : uint4{a0w, a1w, rA_, rB_}; \
    uint4 uA1 = hi ? uint4{rC_, rD_, a6w, a7w} : uint4{a4w, a5w, rC_, rD_}; \
    P0 = __builtin_bit_cast(bf8, uA0); \
    P1 = __builtin_bit_cast(bf8, uA1); \
    unsigned b0w = pack2(pB[0], pB[1]),  b1w = pack2(pB[2], pB[3]); \
    unsigned b2w = pack2(pB[4], pB[5]),  b3w = pack2(pB[6], pB[7]); \
    unsigned b4w = pack2(pB[8], pB[9]),  b5w = pack2(pB[10], pB[11]); \
    unsigned b6w = pack2(pB[12], pB[13]), b7w = pack2(pB[14], pB[15]); \
    unsigned rE_ = (unsigned)__shfl_xor((int)(hi ? b0w : b2w), 32); \
    unsigned rF_ = (unsigned)__shfl_xor((int)(hi ? b1w : b3w), 32); \
    unsigned rG_ = (unsigned)__shfl_xor((int)(hi ? b4w : b6w), 32); \
    unsigned rH_ = (unsigned)__shfl_xor((int)(hi ? b5w : b7w), 32); \
    uint4 uB0 = hi ? uint4{rE_, rF_, b2w, b3w} : uint4{b0w, b1w, rE_, rF_}; \
    uint4 uB1 = hi ? uint4{rG_, rH_, b6w, b7w} : uint4{b4w, b5w, rG_, rH_}; \
    P2 = __builtin_bit_cast(bf8, uB0); \
    P3 = __builtin_bit_cast(bf8, uB1); \
    Va0 = nva0; Va1 = nva1; Va2 = nva2; Va3 = nva3; \
    Vb0 = nvb0; Vb1 = nvb1; Vb2 = nvb2; Vb3 = nvb3; \
    asm volatile("s_waitcnt lgkmcnt(0)" ::: "memory"); \
} while (0)

    // 32 chunks: t=0 (no PV), then t=1..29 staged, t=30,31 unstaged
    ABODY(0, true, false, false);
    ABODY(1, true, false, true);
    ABODY(2, true, false, true);
    for (int t3 = 0; t3 < 9; ++t3) {
        ABODY(0, true, false, true);
        ABODY(1, true, false, true);
        ABODY(2, true, false, true);
    }
    ABODY(0, false, false, true);
    ABODY(1, false, true,  true);

    // tail: PV for the final chunk
    oacc0 = __builtin_amdgcn_mfma_f32_32x32x16_bf16(P0, Va0, oacc0, 0, 0, 0);
    oacc1 = __builtin_amdgcn_mfma_f32_32x32x16_bf16(P0, Vb0, oacc1, 0, 0, 0);
    oacc0 = __builtin_amdgcn_mfma_f32_32x32x16_bf16(P1, Va1, oacc0, 0, 0, 0);
    oacc1 = __builtin_amdgcn_mfma_f32_32x32x16_bf16(P1, Vb1, oacc1, 0, 0, 0);
    oacc0 = __builtin_amdgcn_mfma_f32_32x32x16_bf16(P2, Va2, oacc0, 0, 0, 0);
    oacc1 = __builtin_amdgcn_mfma_f32_32x32x16_bf16(P2, Vb2, oacc1, 0, 0, 0);
    oacc0 = __builtin_amdgcn_mfma_f32_32x32x16_bf16(P3, Va3, oacc0, 0, 0, 0);
    oacc1 = __builtin_amdgcn_mfma_f32_32x32x16_bf16(P3, Vb3, oacc1, 0, 0, 0);

#undef ABODY
#undef STAGE8

    // ---- epilogue: broadcast denominators, normalize, store bf16 ----
    if (hi == 0) bl[wid][l31] = l_run;
    asm volatile("s_waitcnt lgkmcnt(0)" ::: "memory");
#pragma unroll
    for (int r = 0; r < 16; ++r) {
        int q = (r & 3) + 8 * (r >> 2) + 4 * hi;
        float linv = 1.0f / bl[wid][q];
        size_t base = ((size_t)(b * S_LEN + q0 + q)) * EMB + h * HDIM + l31;
        ob[base]      = f2bf(oacc0[r] * linv);
        ob[base + 32] = f2bf(oacc1[r] * linv);
    }
}

// ---------------- final GEMM (BK=64 + XOR-swizzled LDS; out fp32, row remap) ----------------
__global__ void __launch_bounds__(256) k_gemmO(
    const unsigned short* __restrict__ A,
    const unsigned short* __restrict__ B,
    const float* __restrict__ bias,
    float* __restrict__ C,
    int M, int N, int K)
{
    __shared__ __align__(16) unsigned short Sh[16384];
    unsigned short* As = Sh;
    unsigned short* Bs = Sh + 8192;
    const int tid  = threadIdx.x;
    const int lane = tid & 63;
    const int wid  = tid >> 6;
    const int wm = wid >> 1, wn = wid & 1;
    const int l15 = lane & 15, lh = lane >> 4;
    const int mz = l15 & 7;
    const int tm0 = blockIdx.y * 128, tn0 = blockIdx.x * 128;

    f32x4 acc[4][4] = {};

    for (int k0 = 0; k0 < K; k0 += 64) {
        __syncthreads();
#pragma unroll
        for (int rnd = 0; rnd < 4; ++rnd) {
            int cbase = wid * 64 + rnd * 256;
            int c = cbase + lane;
            int row = c >> 3, ps = (c & 7) ^ (row & 7);
            gl_lds16(A + (size_t)(tm0 + row) * K + k0 + ps * 8, &As[cbase * 8]);
            gl_lds16(B + (size_t)(tn0 + row) * K + k0 + ps * 8, &Bs[cbase * 8]);
        }
        __syncthreads();
#pragma unroll
        for (int kk = 0; kk < 2; ++kk) {
            bf8 a[4], b[4];
#pragma unroll
            for (int i = 0; i < 4; ++i) {
                int s = kk * 4 + lh;
                a[i] = *(const bf8*)&As[(wm * 64 + i * 16 + l15) * 64 + (s ^ mz) * 8];
                b[i] = *(const bf8*)&Bs[(wn * 64 + i * 16 + l15) * 64 + (s ^ mz) * 8];
            }
#pragma unroll
            for (int i = 0; i < 4; ++i)
#pragma unroll
                for (int j = 0; j < 4; ++j)
                    acc[i][j] = __builtin_amdgcn_mfma_f32_16x16x32_bf16(a[i], b[j], acc[i][j], 0, 0, 0);
        }
    }

#pragma unroll
    for (int i = 0; i < 4; ++i) {
        const int rowb = tm0 + wm * 64 + i * 16 + lh * 4;
#pragma unroll
        for (int j = 0; j < 4; ++j) {
            const int col = tn0 + wn * 64 + j * 16 + l15;
            float bv = bias[col];
#pragma unroll
            for (int r = 0; r < 4; ++r) {
                int row = rowb + r;
                int bb = row >> 11, ss = row & 2047;
                C[(size_t)(ss * BATCH + bb) * N + col] = acc[i][j][r] + bv;
            }
        }
    }
}

extern "C" void kernel_launch(void* const* d_in, const int* in_sizes, int n_in,
                              void* d_out, int out_size, void* d_ws, size_t ws_size,
                              hipStream_t stream)
{
    (void)in_sizes; (void)n_in; (void)out_size; (void)ws_size;
    const float* query = (const float*)d_in[0];
    const float* wq = (const float*)d_in[1];
    const float* bq = (const float*)d_in[2];
    const float* wk = (const float*)d_in[3];
    const float* bk = (const float*)d_in[4];
    const float* wv = (const float*)d_in[5];
    const float* bv = (const float*)d_in[6];
    const float* wo = (const float*)d_in[7];
    const float* bo = (const float*)d_in[8];

    // ws layout, 41 MB peak:
    //  [0,1)    cosT/sinT
    //  [1,9)    xb
    //  [9,17)   wqb/wkb/wvb/wob (2 MB each)
    //  [17,25)  qb -> ob (attn writes its own rows after reading them)
    //  [25,33)  kb
    //  [33,41)  vT
    char* ws = (char*)d_ws;
    float*          cosT = (float*)(ws + 0);
    float*          sinT = (float*)(ws + (512 << 10));
    unsigned short* xb   = (unsigned short*)(ws + (1  << 20));
    unsigned short* wqb  = (unsigned short*)(ws + (9  << 20));
    unsigned short* wkb  = (unsigned short*)(ws + (11 << 20));
    unsigned short* wvb  = (unsigned short*)(ws + (13 << 20));
    unsigned short* wob  = (unsigned short*)(ws + (15 << 20));
    unsigned short* qb   = (unsigned short*)(ws + (17 << 20));
    unsigned short* ob   = qb;                                  // time-shared
    unsigned short* kb   = (unsigned short*)(ws + (25 << 20));
    unsigned short* vT   = (unsigned short*)(ws + (33 << 20));

    k_prep<<<8704, 256, 0, stream>>>(query, wq, wk, wv, wo,
                                     cosT, sinT, xb, wqb, wkb, wvb, wob);

    dim3 gq(EMB / 128, (S_LEN * BATCH) / 128, 3);    // (8, 32, 3)
    k_gemmQKV<<<gq, 256, 0, stream>>>(xb, wqb, wkb, wvb, bq, bk, bv,
                                      qb, kb, vT, cosT, sinT);

    dim3 g3(S_LEN / 128, BATCH * NHEAD);             // (16, 32)
    k_attn11<<<g3, 256, 0, stream>>>(qb, kb, vT, ob);

    dim3 g1(EMB / 128, (S_LEN * BATCH) / 128);       // (8, 32)
    k_gemmO<<<g1, 256, 0, stream>>>(ob, wob, bo, (float*)d_out, 4096, 1024, 1024);
}

// Round 20
// 152.215 us; speedup vs baseline: 1.0701x; 1.0701x over previous
//
#include <hip/hip_runtime.h>
#include <stdint.h>

#define S_LEN 2048
#define BATCH 2
#define EMB   1024
#define NHEAD 16
#define HDIM  64

typedef __bf16 bf8   __attribute__((ext_vector_type(8)));
typedef float  f32x4 __attribute__((ext_vector_type(4)));
typedef float  f32x16 __attribute__((ext_vector_type(16)));

__device__ __forceinline__ unsigned short f2bf(float f) {
    unsigned u = __builtin_bit_cast(unsigned, f);
    u += 0x7fffu + ((u >> 16) & 1u);          // round-to-nearest-even
    return (unsigned short)(u >> 16);
}
__device__ __forceinline__ float bf2f(unsigned short h) {
    unsigned u = ((unsigned)h) << 16;
    return __builtin_bit_cast(float, u);
}
__device__ __forceinline__ float fexp2(float x) { return __builtin_amdgcn_exp2f(x); }
__device__ __forceinline__ float f3max(float a, float b, float c) { return fmaxf(fmaxf(a, b), c); }

__device__ __forceinline__ void gl_lds16(const unsigned short* g, unsigned short* l) {
    __builtin_amdgcn_global_load_lds(
        (__attribute__((address_space(1))) void*)(void*)g,
        (__attribute__((address_space(3))) void*)(void*)l, 16, 0, 0);
}

// ---------------- fused prologue: rope tables + x cast + 4 weight casts ----------------
__global__ void k_prep(const float* __restrict__ x,
                       const float* __restrict__ w0, const float* __restrict__ w1,
                       const float* __restrict__ w2, const float* __restrict__ w3,
                       float* __restrict__ cosT, float* __restrict__ sinT,
                       unsigned short* __restrict__ xb,
                       unsigned short* __restrict__ o0, unsigned short* __restrict__ o1,
                       unsigned short* __restrict__ o2, unsigned short* __restrict__ o3)
{
    int bid = blockIdx.x;
    if (bid < 512) {
        int idx = bid * 256 + threadIdx.x;      // 2048*64 = 131072
        int s = idx >> 6, d = idx & 63, j = d & 31;
        float inv = exp2f(-13.28771237954945f * ((float)j * (1.0f / 32.0f)));
        float ang = (float)s * inv;
        cosT[idx] = cosf(ang);
        sinT[idx] = sinf(ang);
    } else if (bid < 4608) {
        int id = (bid - 512) * 256 + threadIdx.x;   // 1048576
        int b = id >> 19, rem = id & 524287;
        int s = rem >> 8, e4 = (rem & 255) << 2;
        float4 v = *(const float4*)&x[((size_t)(s * BATCH + b)) * EMB + e4];
        ushort4 o;
        o.x = f2bf(v.x); o.y = f2bf(v.y); o.z = f2bf(v.z); o.w = f2bf(v.w);
        *(ushort4*)&xb[((size_t)(b * S_LEN + s)) * EMB + e4] = o;
    } else {
        int id = (bid - 4608) * 256 + threadIdx.x;  // 1048576
        int seg = id >> 18, r = id & 262143;
        const float* s = seg == 0 ? w0 : seg == 1 ? w1 : seg == 2 ? w2 : w3;
        unsigned short* o = seg == 0 ? o0 : seg == 1 ? o1 : seg == 2 ? o2 : o3;
        float4 v = *(const float4*)&s[(size_t)r * 4];
        ushort4 u;
        u.x = f2bf(v.x); u.y = f2bf(v.y); u.z = f2bf(v.z); u.w = f2bf(v.w);
        *(ushort4*)&o[(size_t)r * 4] = u;
    }
}

// ---------------- merged QKV GEMM, rope fused into q/k epilogues ----------------
// z=2 (V) epilogue: LDS-transposed coalesced store.
__global__ void __launch_bounds__(256) k_gemmQKV(
    const unsigned short* __restrict__ A,
    const unsigned short* __restrict__ Wq, const unsigned short* __restrict__ Wk,
    const unsigned short* __restrict__ Wv,
    const float* __restrict__ bqp, const float* __restrict__ bkp, const float* __restrict__ bvp,
    unsigned short* __restrict__ qout, unsigned short* __restrict__ kout,
    unsigned short* __restrict__ vout,
    const float* __restrict__ cosT, const float* __restrict__ sinT)
{
    __shared__ __align__(16) unsigned short Sh[8704];   // As[0,4096) Bs[4096,8192); V-transpose [128][68]
    unsigned short* As = Sh;
    unsigned short* Bs = Sh + 4096;
    const int z = blockIdx.z;
    const unsigned short* B = z == 0 ? Wq : z == 1 ? Wk : Wv;
    const float* bias = z == 0 ? bqp : z == 1 ? bkp : bvp;
    const int tid  = threadIdx.x;
    const int lane = tid & 63;
    const int wid  = tid >> 6;
    const int wm = wid >> 1, wn = wid & 1;
    const int l15 = lane & 15, lh = lane >> 4;
    const int tm0 = blockIdx.y * 128, tn0 = blockIdx.x * 128;
    const int K = 1024;

    f32x4 acc[4][4] = {};

    for (int k0 = 0; k0 < K; k0 += 32) {
        __syncthreads();
#pragma unroll
        for (int rnd = 0; rnd < 2; ++rnd) {
            int cbase = wid * 64 + rnd * 256;          // wave-uniform chunk base
            int c = cbase + lane;
            int row = c >> 2, co = (c & 3) * 8;
            gl_lds16(A + (size_t)(tm0 + row) * K + k0 + co, &As[cbase * 8]);
            gl_lds16(B + (size_t)(tn0 + row) * K + k0 + co, &Bs[cbase * 8]);
        }
        __syncthreads();
        bf8 a[4], b[4];
#pragma unroll
        for (int i = 0; i < 4; ++i) {
            a[i] = *(const bf8*)&As[(wm * 64 + i * 16 + l15) * 32 + lh * 8];
            b[i] = *(const bf8*)&Bs[(wn * 64 + i * 16 + l15) * 32 + lh * 8];
        }
#pragma unroll
        for (int i = 0; i < 4; ++i)
#pragma unroll
            for (int j = 0; j < 4; ++j)
                acc[i][j] = __builtin_amdgcn_mfma_f32_16x16x32_bf16(a[i], b[j], acc[i][j], 0, 0, 0);
    }

    if (z < 2) {
        unsigned short* C = z ? kout : qout;
        const float f = z ? 1.0f : 0.125f * 1.44269504089f;
#pragma unroll
        for (int i = 0; i < 4; ++i) {
            const int rowb = tm0 + wm * 64 + i * 16 + lh * 4;
#pragma unroll
            for (int j = 0; j < 2; ++j) {
                const int col = tn0 + wn * 64 + j * 16 + l15;   // d = j*16+l15 in [0,32)
                const int d = j * 16 + l15;
#pragma unroll
                for (int r = 0; r < 4; ++r) {
                    int m = rowb + r;
                    int sq = m & (S_LEN - 1);
                    float x1 = acc[i][j][r]     + bias[col];
                    float x2 = acc[i][j + 2][r] + bias[col + 32];
                    float c  = cosT[sq * 64 + d] * f;
                    float sn = sinT[sq * 64 + d] * f;
                    C[(size_t)m * EMB + col]      = f2bf(x1 * c - x2 * sn);
                    C[(size_t)m * EMB + col + 32] = f2bf(x2 * c + x1 * sn);
                }
            }
        }
    } else {
        // V: two m-half passes through an LDS [128 f][68] transpose tile,
        // then fully-coalesced 16B stores (8 lanes x 16B = 128B contiguous).
        __syncthreads();                 // all waves done with As/Bs
#pragma unroll
        for (int p = 0; p < 2; ++p) {
            if (wm == p) {
#pragma unroll
                for (int i = 0; i < 4; ++i) {
                    const int mloc = i * 16 + lh * 4;           // 0..63 within half
#pragma unroll
                    for (int j = 0; j < 4; ++j) {
                        const int fcol = wn * 64 + j * 16 + l15;
                        float bv = bias[tn0 + fcol];
#pragma unroll
                        for (int r = 0; r < 4; ++r)
                            Sh[fcol * 68 + mloc + r] = f2bf(acc[i][j][r] + bv);
                    }
                }
            }
            __syncthreads();
#pragma unroll
            for (int g = 0; g < 4; ++g) {
                int fcol = g * 32 + (tid >> 3);
                int mo = (tid & 7) * 8;
                *(uint4*)&vout[(size_t)(tn0 + fcol) * 4096 + tm0 + p * 64 + mo] =
                    *(const uint4*)&Sh[fcol * 68 + mo];
            }
            __syncthreads();
        }
    }
}

// ---------------- flash attention v17: deferred PV, race-fixed ----------------
__global__ void __launch_bounds__(256) k_attn11(
    const unsigned short* __restrict__ qb,
    const unsigned short* __restrict__ kb,
    const unsigned short* __restrict__ vT,
    unsigned short* __restrict__ ob)
{
    // Sm shorts: K(buf) at buf*4096, V(buf) at 12288 + buf*4096  (bytes: *2)
    __shared__ __align__(16) unsigned short Sm[24576];
    __shared__ float bl[4][32];
    const int tid = threadIdx.x, lane = tid & 63, wid = tid >> 6;
    const int l31 = lane & 31, hi = lane >> 5;
    const int bh = blockIdx.y;
    const int b = bh >> 4, h = bh & 15;
    const int q0 = blockIdx.x * 128 + wid * 32;

    const unsigned short* qrow = qb + ((size_t)(b * S_LEN + q0 + l31)) * EMB + h * HDIM + hi * 8;
    bf8 qf[4];
#pragma unroll
    for (int c = 0; c < 4; ++c) qf[c] = *(const bf8*)(qrow + c * 16);

    // ---- hoisted ds-read per-lane byte offsets (chunk A rows; B = +4096 imm) ----
    const int mz = l31 & 7;
    const int koA0 = l31 * 128 + (((0 * 2 + hi) ^ mz) << 4);
    const int koA1 = l31 * 128 + (((1 * 2 + hi) ^ mz) << 4);
    const int koA2 = l31 * 128 + (((2 * 2 + hi) ^ mz) << 4);
    const int koA3 = l31 * 128 + (((3 * 2 + hi) ^ mz) << 4);
    const char* ldsc = (const char*)Sm;

    // ---- hoisted stage per-lane byte offsets ----
    const int srow = lane >> 3, sp = lane & 7;
    const int r0 = wid * 16 + srow,     p0s = sp ^ (r0 & 7);
    const int r1 = wid * 16 + 8 + srow, p1s = sp ^ (r1 & 7);
    const int kgo0 = (r0 * EMB + p0s * 8) * 2, kgo1 = (r1 * EMB + p1s * 8) * 2;
    const int vgo0 = (r0 * (S_LEN * BATCH) + p0s * 8) * 2, vgo1 = (r1 * (S_LEN * BATCH) + p1s * 8) * 2;

    const unsigned short* kS = kb + ((size_t)(b * S_LEN)) * EMB + h * HDIM;
    const unsigned short* vS = vT + ((size_t)h * HDIM) * (S_LEN * BATCH) + b * S_LEN;

#define STAGE8(DBUF) do { \
    gl_lds16((const unsigned short*)((const char*)kS + kgo0), Sm + (DBUF) * 4096 + wid * 1024); \
    gl_lds16((const unsigned short*)((const char*)vS + vgo0), Sm + 12288 + (DBUF) * 4096 + wid * 1024); \
    gl_lds16((const unsigned short*)((const char*)kS + kgo1), Sm + (DBUF) * 4096 + wid * 1024 + 512); \
    gl_lds16((const unsigned short*)((const char*)vS + vgo1), Sm + 12288 + (DBUF) * 4096 + wid * 1024 + 512); \
    kS += 64 * EMB; vS += 64; } while (0)

    auto pack2 = [](float lo, float hh) -> unsigned {
        unsigned short a  = __builtin_bit_cast(unsigned short, (__bf16)lo);
        unsigned short bb = __builtin_bit_cast(unsigned short, (__bf16)hh);
        return ((unsigned)bb << 16) | a;
    };

    float m_run = 0.f, l_run = 0.f;
    f32x16 oacc0 = {}, oacc1 = {};
    const f32x16 Z16 = {};

    // persistent cross-iteration fragments (previous chunk's P and V)
    bf8 P0 = {}, P1 = {}, P2 = {}, P3 = {};
    bf8 Va0 = {}, Va1 = {}, Va2 = {}, Va3 = {};
    bf8 Vb0 = {}, Vb1 = {}, Vb2 = {}, Vb3 = {};

    STAGE8(0);
    STAGE8(1);

#define ABODY(BUF, DOSTG, LASTW, DOPV) do { \
    if (LASTW) asm volatile("s_waitcnt vmcnt(0)" ::: "memory"); \
    else       asm volatile("s_waitcnt vmcnt(4)" ::: "memory"); \
    __builtin_amdgcn_s_barrier(); \
    if (DOSTG) STAGE8(((BUF) + 2) % 3); \
    bf8 ka0 = *(const bf8*)(ldsc + koA0 + (BUF) * 8192); \
    bf8 ka1 = *(const bf8*)(ldsc + koA1 + (BUF) * 8192); \
    bf8 ka2 = *(const bf8*)(ldsc + koA2 + (BUF) * 8192); \
    bf8 ka3 = *(const bf8*)(ldsc + koA3 + (BUF) * 8192); \
    bf8 kb0 = *(const bf8*)(ldsc + koA0 + (BUF) * 8192 + 4096); \
    bf8 kb1 = *(const bf8*)(ldsc + koA1 + (BUF) * 8192 + 4096); \
    bf8 kb2 = *(const bf8*)(ldsc + koA2 + (BUF) * 8192 + 4096); \
    bf8 kb3 = *(const bf8*)(ldsc + koA3 + (BUF) * 8192 + 4096); \
    bf8 nva0 = *(const bf8*)(ldsc + koA0 + 24576 + (BUF) * 8192); \
    bf8 nva1 = *(const bf8*)(ldsc + koA1 + 24576 + (BUF) * 8192); \
    bf8 nva2 = *(const bf8*)(ldsc + koA2 + 24576 + (BUF) * 8192); \
    bf8 nva3 = *(const bf8*)(ldsc + koA3 + 24576 + (BUF) * 8192); \
    bf8 nvb0 = *(const bf8*)(ldsc + koA0 + 24576 + (BUF) * 8192 + 4096); \
    bf8 nvb1 = *(const bf8*)(ldsc + koA1 + 24576 + (BUF) * 8192 + 4096); \
    bf8 nvb2 = *(const bf8*)(ldsc + koA2 + 24576 + (BUF) * 8192 + 4096); \
    bf8 nvb3 = *(const bf8*)(ldsc + koA3 + 24576 + (BUF) * 8192 + 4096); \
    __builtin_amdgcn_s_setprio(1); \
    f32x16 stA = __builtin_amdgcn_mfma_f32_32x32x16_bf16(ka0, qf[0], Z16, 0, 0, 0); \
    f32x16 stB = __builtin_amdgcn_mfma_f32_32x32x16_bf16(kb0, qf[0], Z16, 0, 0, 0); \
    stA = __builtin_amdgcn_mfma_f32_32x32x16_bf16(ka1, qf[1], stA, 0, 0, 0); \
    stB = __builtin_amdgcn_mfma_f32_32x32x16_bf16(kb1, qf[1], stB, 0, 0, 0); \
    stA = __builtin_amdgcn_mfma_f32_32x32x16_bf16(ka2, qf[2], stA, 0, 0, 0); \
    stB = __builtin_amdgcn_mfma_f32_32x32x16_bf16(kb2, qf[2], stB, 0, 0, 0); \
    stA = __builtin_amdgcn_mfma_f32_32x32x16_bf16(ka3, qf[3], stA, 0, 0, 0); \
    stB = __builtin_amdgcn_mfma_f32_32x32x16_bf16(kb3, qf[3], stB, 0, 0, 0); \
    if (DOPV) { \
        oacc0 = __builtin_amdgcn_mfma_f32_32x32x16_bf16(P0, Va0, oacc0, 0, 0, 0); \
        oacc1 = __builtin_amdgcn_mfma_f32_32x32x16_bf16(P0, Vb0, oacc1, 0, 0, 0); \
        oacc0 = __builtin_amdgcn_mfma_f32_32x32x16_bf16(P1, Va1, oacc0, 0, 0, 0); \
        oacc1 = __builtin_amdgcn_mfma_f32_32x32x16_bf16(P1, Vb1, oacc1, 0, 0, 0); \
        oacc0 = __builtin_amdgcn_mfma_f32_32x32x16_bf16(P2, Va2, oacc0, 0, 0, 0); \
        oacc1 = __builtin_amdgcn_mfma_f32_32x32x16_bf16(P2, Vb2, oacc1, 0, 0, 0); \
        oacc0 = __builtin_amdgcn_mfma_f32_32x32x16_bf16(P3, Va3, oacc0, 0, 0, 0); \
        oacc1 = __builtin_amdgcn_mfma_f32_32x32x16_bf16(P3, Vb3, oacc1, 0, 0, 0); \
    } \
    __builtin_amdgcn_s_setprio(0); \
    float g0 = f3max(f3max(stA[0], stA[1], stA[2]),  f3max(stA[3], stA[4], stA[5]),  f3max(stA[6], stA[7], stA[8])); \
    float g1 = f3max(f3max(stA[9], stA[10], stA[11]), f3max(stA[12], stA[13], stA[14]), fmaxf(stA[15], stB[0])); \
    float g2 = f3max(f3max(stB[1], stB[2], stB[3]),  f3max(stB[4], stB[5], stB[6]),  f3max(stB[7], stB[8], stB[9])); \
    float g3 = f3max(f3max(stB[10], stB[11], stB[12]), f3max(stB[13], stB[14], stB[15]), fmaxf(g0, g1)); \
    float pmax = f3max(g2, g3, g0); \
    pmax = fmaxf(pmax, __shfl_xor(pmax, 32)); \
    if (!__all(pmax - m_run <= 11.54f)) { \
        float mnew = fmaxf(m_run, pmax); \
        float corr = fexp2(m_run - mnew); \
        l_run *= corr; m_run = mnew; \
        if (hi == 0) bl[wid][l31] = corr; \
        asm volatile("s_waitcnt lgkmcnt(0)" ::: "memory"); \
        _Pragma("unroll") for (int r = 0; r < 16; ++r) { \
            float c2 = bl[wid][(r & 3) + 8 * (r >> 2) + 4 * hi]; \
            oacc0[r] *= c2; oacc1[r] *= c2; } \
    } \
    float pA[16], pB[16]; \
    _Pragma("unroll") for (int r = 0; r < 16; ++r) pA[r] = fexp2(stA[r] - m_run); \
    _Pragma("unroll") for (int r = 0; r < 16; ++r) pB[r] = fexp2(stB[r] - m_run); \
    float sA = (((pA[0] + pA[1]) + (pA[2] + pA[3])) + ((pA[4] + pA[5]) + (pA[6] + pA[7]))) \
             + (((pA[8] + pA[9]) + (pA[10] + pA[11])) + ((pA[12] + pA[13]) + (pA[14] + pA[15]))); \
    float sB = (((pB[0] + pB[1]) + (pB[2] + pB[3])) + ((pB[4] + pB[5]) + (pB[6] + pB[7]))) \
             + (((pB[8] + pB[9]) + (pB[10] + pB[11])) + ((pB[12] + pB[13]) + (pB[14] + pB[15]))); \
    float psum = sA + sB; \
    psum += __shfl_xor(psum, 32); \
    l_run += psum; \
    unsigned a0w = pack2(pA[0], pA[1]),  a1w = pack2(pA[2], pA[3]); \
    unsigned a2w = pack2(pA[4], pA[5]),  a3w = pack2(pA[6], pA[7]); \
    unsigned a4w = pack2(pA[8], pA[9]),  a5w = pack2(pA[10], pA[11]); \
    unsigned a6w = pack2(pA[12], pA[13]), a7w = pack2(pA[14], pA[15]); \
    unsigned rA_ = (unsigned)__shfl_xor((int)(hi ? a0w : a2w), 32); \
    unsigned rB_ = (unsigned)__shfl_xor((int)(hi ? a1w : a3w), 32); \
    unsigned rC_ = (unsigned)__shfl_xor((int)(hi ? a4w : a6w), 32); \
    unsigned rD_ = (unsigned)__shfl_xor((int)(hi ? a5w : a7w), 32); \
    uint4 uA0 = hi ? uint4{rA_, rB_, a2w, a3w} : uint4{a0w, a1w, rA_, rB_}; \
    uint4 uA1 = hi ? uint4{rC_, rD_, a6w, a7w} : uint4{a4w, a5w, rC_, rD_}; \
    P0 = __builtin_bit_cast(bf8, uA0); \
    P1 = __builtin_bit_cast(bf8, uA1); \
    unsigned b0w = pack2(pB[0], pB[1]),  b1w = pack2(pB[2], pB[3]); \
    unsigned b2w = pack2(pB[4], pB[5]),  b3w = pack2(pB[6], pB[7]); \
    unsigned b4w = pack2(pB[8], pB[9]),  b5w = pack2(pB[10], pB[11]); \
    unsigned b6w = pack2(pB[12], pB[13]), b7w = pack2(pB[14], pB[15]); \
    unsigned rE_ = (unsigned)__shfl_xor((int)(hi ? b0w : b2w), 32); \
    unsigned rF_ = (unsigned)__shfl_xor((int)(hi ? b1w : b3w), 32); \
    unsigned rG_ = (unsigned)__shfl_xor((int)(hi ? b4w : b6w), 32); \
    unsigned rH_ = (unsigned)__shfl_xor((int)(hi ? b5w : b7w), 32); \
    uint4 uB0 = hi ? uint4{rE_, rF_, b2w, b3w} : uint4{b0w, b1w, rE_, rF_}; \
    uint4 uB1 = hi ? uint4{rG_, rH_, b6w, b7w} : uint4{b4w, b5w, rG_, rH_}; \
    P2 = __builtin_bit_cast(bf8, uB0); \
    P3 = __builtin_bit_cast(bf8, uB1); \
    Va0 = nva0; Va1 = nva1; Va2 = nva2; Va3 = nva3; \
    Vb0 = nvb0; Vb1 = nvb1; Vb2 = nvb2; Vb3 = nvb3; \
    asm volatile("s_waitcnt lgkmcnt(0)" ::: "memory"); \
} while (0)

    // 32 chunks: t=0 (no PV), then t=1..29 staged, t=30,31 unstaged
    ABODY(0, true, false, false);
    ABODY(1, true, false, true);
    ABODY(2, true, false, true);
    for (int t3 = 0; t3 < 9; ++t3) {
        ABODY(0, true, false, true);
        ABODY(1, true, false, true);
        ABODY(2, true, false, true);
    }
    ABODY(0, false, false, true);
    ABODY(1, false, true,  true);

    // tail: PV for the final chunk
    oacc0 = __builtin_amdgcn_mfma_f32_32x32x16_bf16(P0, Va0, oacc0, 0, 0, 0);
    oacc1 = __builtin_amdgcn_mfma_f32_32x32x16_bf16(P0, Vb0, oacc1, 0, 0, 0);
    oacc0 = __builtin_amdgcn_mfma_f32_32x32x16_bf16(P1, Va1, oacc0, 0, 0, 0);
    oacc1 = __builtin_amdgcn_mfma_f32_32x32x16_bf16(P1, Vb1, oacc1, 0, 0, 0);
    oacc0 = __builtin_amdgcn_mfma_f32_32x32x16_bf16(P2, Va2, oacc0, 0, 0, 0);
    oacc1 = __builtin_amdgcn_mfma_f32_32x32x16_bf16(P2, Vb2, oacc1, 0, 0, 0);
    oacc0 = __builtin_amdgcn_mfma_f32_32x32x16_bf16(P3, Va3, oacc0, 0, 0, 0);
    oacc1 = __builtin_amdgcn_mfma_f32_32x32x16_bf16(P3, Vb3, oacc1, 0, 0, 0);

#undef ABODY
#undef STAGE8

    // ---- epilogue: broadcast denominators, normalize, store bf16 ----
    if (hi == 0) bl[wid][l31] = l_run;
    asm volatile("s_waitcnt lgkmcnt(0)" ::: "memory");
#pragma unroll
    for (int r = 0; r < 16; ++r) {
        int q = (r & 3) + 8 * (r >> 2) + 4 * hi;
        float linv = 1.0f / bl[wid][q];
        size_t base = ((size_t)(b * S_LEN + q0 + q)) * EMB + h * HDIM + l31;
        ob[base]      = f2bf(oacc0[r] * linv);
        ob[base + 32] = f2bf(oacc1[r] * linv);
    }
}

// ---------------- final GEMM (out fp32, row remap) ----------------
template<int EPI, typename OutT>
__global__ void __launch_bounds__(256) k_gemm(
    const unsigned short* __restrict__ A,
    const unsigned short* __restrict__ B,
    const float* __restrict__ bias,
    OutT* __restrict__ C,
    int M, int N, int K)
{
    __shared__ __align__(16) unsigned short As[128 * 32];
    __shared__ __align__(16) unsigned short Bs[128 * 32];
    const int tid  = threadIdx.x;
    const int lane = tid & 63;
    const int wid  = tid >> 6;
    const int wm = wid >> 1, wn = wid & 1;
    const int l15 = lane & 15, lh = lane >> 4;
    const int tm0 = blockIdx.y * 128, tn0 = blockIdx.x * 128;

    f32x4 acc[4][4] = {};

    for (int k0 = 0; k0 < K; k0 += 32) {
        __syncthreads();
#pragma unroll
        for (int rnd = 0; rnd < 2; ++rnd) {
            int cbase = wid * 64 + rnd * 256;
            int c = cbase + lane;
            int row = c >> 2, co = (c & 3) * 8;
            gl_lds16(A + (size_t)(tm0 + row) * K + k0 + co, &As[cbase * 8]);
            gl_lds16(B + (size_t)(tn0 + row) * K + k0 + co, &Bs[cbase * 8]);
        }
        __syncthreads();
        bf8 a[4], b[4];
#pragma unroll
        for (int i = 0; i < 4; ++i) {
            a[i] = *(const bf8*)&As[(wm * 64 + i * 16 + l15) * 32 + lh * 8];
            b[i] = *(const bf8*)&Bs[(wn * 64 + i * 16 + l15) * 32 + lh * 8];
        }
#pragma unroll
        for (int i = 0; i < 4; ++i)
#pragma unroll
            for (int j = 0; j < 4; ++j)
                acc[i][j] = __builtin_amdgcn_mfma_f32_16x16x32_bf16(a[i], b[j], acc[i][j], 0, 0, 0);
    }

#pragma unroll
    for (int i = 0; i < 4; ++i) {
        const int rowb = tm0 + wm * 64 + i * 16 + lh * 4;
#pragma unroll
        for (int j = 0; j < 4; ++j) {
            const int col = tn0 + wn * 64 + j * 16 + l15;
#pragma unroll
            for (int r = 0; r < 4; ++r) {
                float v = acc[i][j][r];
                int row = rowb + r;
                if (EPI == 0) {
                    v += bias[col];
                    C[(size_t)row * N + col] = (OutT)f2bf(v);
                } else {
                    v += bias[col];
                    int bb = row >> 11, ss = row & 2047;
                    ((float*)C)[(size_t)(ss * BATCH + bb) * N + col] = v;
                }
            }
        }
    }
}

extern "C" void kernel_launch(void* const* d_in, const int* in_sizes, int n_in,
                              void* d_out, int out_size, void* d_ws, size_t ws_size,
                              hipStream_t stream)
{
    (void)in_sizes; (void)n_in; (void)out_size; (void)ws_size;
    const float* query = (const float*)d_in[0];
    const float* wq = (const float*)d_in[1];
    const float* bq = (const float*)d_in[2];
    const float* wk = (const float*)d_in[3];
    const float* bk = (const float*)d_in[4];
    const float* wv = (const float*)d_in[5];
    const float* bv = (const float*)d_in[6];
    const float* wo = (const float*)d_in[7];
    const float* bo = (const float*)d_in[8];

    // ws layout, 41 MB peak:
    //  [0,1)    cosT/sinT
    //  [1,9)    xb
    //  [9,17)   wqb/wkb/wvb/wob (2 MB each)
    //  [17,25)  qb -> ob (attn writes its own rows after reading them)
    //  [25,33)  kb
    //  [33,41)  vT
    char* ws = (char*)d_ws;
    float*          cosT = (float*)(ws + 0);
    float*          sinT = (float*)(ws + (512 << 10));
    unsigned short* xb   = (unsigned short*)(ws + (1  << 20));
    unsigned short* wqb  = (unsigned short*)(ws + (9  << 20));
    unsigned short* wkb  = (unsigned short*)(ws + (11 << 20));
    unsigned short* wvb  = (unsigned short*)(ws + (13 << 20));
    unsigned short* wob  = (unsigned short*)(ws + (15 << 20));
    unsigned short* qb   = (unsigned short*)(ws + (17 << 20));
    unsigned short* ob   = qb;                                  // time-shared
    unsigned short* kb   = (unsigned short*)(ws + (25 << 20));
    unsigned short* vT   = (unsigned short*)(ws + (33 << 20));

    k_prep<<<8704, 256, 0, stream>>>(query, wq, wk, wv, wo,
                                     cosT, sinT, xb, wqb, wkb, wvb, wob);

    dim3 gq(EMB / 128, (S_LEN * BATCH) / 128, 3);    // (8, 32, 3)
    k_gemmQKV<<<gq, 256, 0, stream>>>(xb, wqb, wkb, wvb, bq, bk, bv,
                                      qb, kb, vT, cosT, sinT);

    dim3 g3(S_LEN / 128, BATCH * NHEAD);             // (16, 32)
    k_attn11<<<g3, 256, 0, stream>>>(qb, kb, vT, ob);

    dim3 g1(EMB / 128, (S_LEN * BATCH) / 128);       // (8, 32)
    k_gemm<1, float><<<g1, 256, 0, stream>>>(ob, wob, bo, (float*)d_out, 4096, 1024, 1024);
}

// Round 21
// 150.578 us; speedup vs baseline: 1.0818x; 1.0109x over previous
//
#include <hip/hip_runtime.h>
#include <stdint.h>

#define S_LEN 2048
#define BATCH 2
#define EMB   1024
#define NHEAD 16
#define HDIM  64

typedef __bf16 bf8   __attribute__((ext_vector_type(8)));
typedef float  f32x4 __attribute__((ext_vector_type(4)));
typedef float  f32x16 __attribute__((ext_vector_type(16)));

__device__ __forceinline__ unsigned short f2bf(float f) {
    unsigned u = __builtin_bit_cast(unsigned, f);
    u += 0x7fffu + ((u >> 16) & 1u);          // round-to-nearest-even
    return (unsigned short)(u >> 16);
}
__device__ __forceinline__ float bf2f(unsigned short h) {
    unsigned u = ((unsigned)h) << 16;
    return __builtin_bit_cast(float, u);
}
__device__ __forceinline__ float fexp2(float x) { return __builtin_amdgcn_exp2f(x); }
__device__ __forceinline__ float f3max(float a, float b, float c) { return fmaxf(fmaxf(a, b), c); }

__device__ __forceinline__ void gl_lds16(const unsigned short* g, unsigned short* l) {
    __builtin_amdgcn_global_load_lds(
        (__attribute__((address_space(1))) void*)(void*)g,
        (__attribute__((address_space(3))) void*)(void*)l, 16, 0, 0);
}

// ---------------- fused prologue: rope tables + x cast + 4 weight casts ----------------
__global__ void k_prep(const float* __restrict__ x,
                       const float* __restrict__ w0, const float* __restrict__ w1,
                       const float* __restrict__ w2, const float* __restrict__ w3,
                       float* __restrict__ cosT, float* __restrict__ sinT,
                       unsigned short* __restrict__ xb,
                       unsigned short* __restrict__ o0, unsigned short* __restrict__ o1,
                       unsigned short* __restrict__ o2, unsigned short* __restrict__ o3)
{
    int bid = blockIdx.x;
    if (bid < 512) {
        int idx = bid * 256 + threadIdx.x;      // 2048*64 = 131072
        int s = idx >> 6, d = idx & 63, j = d & 31;
        float inv = exp2f(-13.28771237954945f * ((float)j * (1.0f / 32.0f)));
        float ang = (float)s * inv;
        cosT[idx] = cosf(ang);
        sinT[idx] = sinf(ang);
    } else if (bid < 4608) {
        int id = (bid - 512) * 256 + threadIdx.x;   // 1048576
        int b = id >> 19, rem = id & 524287;
        int s = rem >> 8, e4 = (rem & 255) << 2;
        float4 v = *(const float4*)&x[((size_t)(s * BATCH + b)) * EMB + e4];
        ushort4 o;
        o.x = f2bf(v.x); o.y = f2bf(v.y); o.z = f2bf(v.z); o.w = f2bf(v.w);
        *(ushort4*)&xb[((size_t)(b * S_LEN + s)) * EMB + e4] = o;
    } else {
        int id = (bid - 4608) * 256 + threadIdx.x;  // 1048576
        int seg = id >> 18, r = id & 262143;
        const float* s = seg == 0 ? w0 : seg == 1 ? w1 : seg == 2 ? w2 : w3;
        unsigned short* o = seg == 0 ? o0 : seg == 1 ? o1 : seg == 2 ? o2 : o3;
        float4 v = *(const float4*)&s[(size_t)r * 4];
        ushort4 u;
        u.x = f2bf(v.x); u.y = f2bf(v.y); u.z = f2bf(v.z); u.w = f2bf(v.w);
        *(ushort4*)&o[(size_t)r * 4] = u;
    }
}

// ---------------- merged QKV GEMM, rope fused into q/k epilogues ----------------
// z=2 (V) epilogue: LDS-transposed coalesced store.
__global__ void __launch_bounds__(256) k_gemmQKV(
    const unsigned short* __restrict__ A,
    const unsigned short* __restrict__ Wq, const unsigned short* __restrict__ Wk,
    const unsigned short* __restrict__ Wv,
    const float* __restrict__ bqp, const float* __restrict__ bkp, const float* __restrict__ bvp,
    unsigned short* __restrict__ qout, unsigned short* __restrict__ kout,
    unsigned short* __restrict__ vout,
    const float* __restrict__ cosT, const float* __restrict__ sinT)
{
    __shared__ __align__(16) unsigned short Sh[8704];   // As[0,4096) Bs[4096,8192); V-transpose [128][68]
    unsigned short* As = Sh;
    unsigned short* Bs = Sh + 4096;
    const int z = blockIdx.z;
    const unsigned short* B = z == 0 ? Wq : z == 1 ? Wk : Wv;
    const float* bias = z == 0 ? bqp : z == 1 ? bkp : bvp;
    const int tid  = threadIdx.x;
    const int lane = tid & 63;
    const int wid  = tid >> 6;
    const int wm = wid >> 1, wn = wid & 1;
    const int l15 = lane & 15, lh = lane >> 4;
    const int tm0 = blockIdx.y * 128, tn0 = blockIdx.x * 128;
    const int K = 1024;

    f32x4 acc[4][4] = {};

    for (int k0 = 0; k0 < K; k0 += 32) {
        __syncthreads();
#pragma unroll
        for (int rnd = 0; rnd < 2; ++rnd) {
            int cbase = wid * 64 + rnd * 256;          // wave-uniform chunk base
            int c = cbase + lane;
            int row = c >> 2, co = (c & 3) * 8;
            gl_lds16(A + (size_t)(tm0 + row) * K + k0 + co, &As[cbase * 8]);
            gl_lds16(B + (size_t)(tn0 + row) * K + k0 + co, &Bs[cbase * 8]);
        }
        __syncthreads();
        bf8 a[4], b[4];
#pragma unroll
        for (int i = 0; i < 4; ++i) {
            a[i] = *(const bf8*)&As[(wm * 64 + i * 16 + l15) * 32 + lh * 8];
            b[i] = *(const bf8*)&Bs[(wn * 64 + i * 16 + l15) * 32 + lh * 8];
        }
#pragma unroll
        for (int i = 0; i < 4; ++i)
#pragma unroll
            for (int j = 0; j < 4; ++j)
                acc[i][j] = __builtin_amdgcn_mfma_f32_16x16x32_bf16(a[i], b[j], acc[i][j], 0, 0, 0);
    }

    if (z < 2) {
        unsigned short* C = z ? kout : qout;
        const float f = z ? 1.0f : 0.125f * 1.44269504089f;
#pragma unroll
        for (int i = 0; i < 4; ++i) {
            const int rowb = tm0 + wm * 64 + i * 16 + lh * 4;
#pragma unroll
            for (int j = 0; j < 2; ++j) {
                const int col = tn0 + wn * 64 + j * 16 + l15;   // d = j*16+l15 in [0,32)
                const int d = j * 16 + l15;
#pragma unroll
                for (int r = 0; r < 4; ++r) {
                    int m = rowb + r;
                    int sq = m & (S_LEN - 1);
                    float x1 = acc[i][j][r]     + bias[col];
                    float x2 = acc[i][j + 2][r] + bias[col + 32];
                    float c  = cosT[sq * 64 + d] * f;
                    float sn = sinT[sq * 64 + d] * f;
                    C[(size_t)m * EMB + col]      = f2bf(x1 * c - x2 * sn);
                    C[(size_t)m * EMB + col + 32] = f2bf(x2 * c + x1 * sn);
                }
            }
        }
    } else {
        // V: two m-half passes through an LDS [128 f][68] transpose tile,
        // then fully-coalesced 16B stores (8 lanes x 16B = 128B contiguous).
        __syncthreads();                 // all waves done with As/Bs
#pragma unroll
        for (int p = 0; p < 2; ++p) {
            if (wm == p) {
#pragma unroll
                for (int i = 0; i < 4; ++i) {
                    const int mloc = i * 16 + lh * 4;           // 0..63 within half
#pragma unroll
                    for (int j = 0; j < 4; ++j) {
                        const int fcol = wn * 64 + j * 16 + l15;
                        float bv = bias[tn0 + fcol];
#pragma unroll
                        for (int r = 0; r < 4; ++r)
                            Sh[fcol * 68 + mloc + r] = f2bf(acc[i][j][r] + bv);
                    }
                }
            }
            __syncthreads();
#pragma unroll
            for (int g = 0; g < 4; ++g) {
                int fcol = g * 32 + (tid >> 3);
                int mo = (tid & 7) * 8;
                *(uint4*)&vout[(size_t)(tn0 + fcol) * 4096 + tm0 + p * 64 + mo] =
                    *(const uint4*)&Sh[fcol * 68 + mo];
            }
            __syncthreads();
        }
    }
}

// ---------------- flash attention v18: v17 + XCD-aware block swizzle (T1) ----------------
// grid: flat 512 blocks. Work id w = (bid%8)*64 + bid/8 (bijective: 512 = 8*64), so
// under round-robin block->XCD dispatch each XCD processes 4 complete bh groups and
// their 512 KB K/V working sets stay L2-local instead of being re-fetched 8x.
__global__ void __launch_bounds__(256) k_attn11(
    const unsigned short* __restrict__ qb,
    const unsigned short* __restrict__ kb,
    const unsigned short* __restrict__ vT,
    unsigned short* __restrict__ ob)
{
    // Sm shorts: K(buf) at buf*4096, V(buf) at 12288 + buf*4096  (bytes: *2)
    __shared__ __align__(16) unsigned short Sm[24576];
    __shared__ float bl[4][32];
    const int tid = threadIdx.x, lane = tid & 63, wid = tid >> 6;
    const int l31 = lane & 31, hi = lane >> 5;
    const int bid = blockIdx.x;
    const int w   = (bid & 7) * 64 + (bid >> 3);    // XCD-contiguous work id
    const int bh  = w >> 4;                          // 0..31
    const int qx  = w & 15;                          // 0..15
    const int b = bh >> 4, h = bh & 15;
    const int q0 = qx * 128 + wid * 32;

    const unsigned short* qrow = qb + ((size_t)(b * S_LEN + q0 + l31)) * EMB + h * HDIM + hi * 8;
    bf8 qf[4];
#pragma unroll
    for (int c = 0; c < 4; ++c) qf[c] = *(const bf8*)(qrow + c * 16);

    // ---- hoisted ds-read per-lane byte offsets (chunk A rows; B = +4096 imm) ----
    const int mz = l31 & 7;
    const int koA0 = l31 * 128 + (((0 * 2 + hi) ^ mz) << 4);
    const int koA1 = l31 * 128 + (((1 * 2 + hi) ^ mz) << 4);
    const int koA2 = l31 * 128 + (((2 * 2 + hi) ^ mz) << 4);
    const int koA3 = l31 * 128 + (((3 * 2 + hi) ^ mz) << 4);
    const char* ldsc = (const char*)Sm;

    // ---- hoisted stage per-lane byte offsets ----
    const int srow = lane >> 3, sp = lane & 7;
    const int r0 = wid * 16 + srow,     p0s = sp ^ (r0 & 7);
    const int r1 = wid * 16 + 8 + srow, p1s = sp ^ (r1 & 7);
    const int kgo0 = (r0 * EMB + p0s * 8) * 2, kgo1 = (r1 * EMB + p1s * 8) * 2;
    const int vgo0 = (r0 * (S_LEN * BATCH) + p0s * 8) * 2, vgo1 = (r1 * (S_LEN * BATCH) + p1s * 8) * 2;

    const unsigned short* kS = kb + ((size_t)(b * S_LEN)) * EMB + h * HDIM;
    const unsigned short* vS = vT + ((size_t)h * HDIM) * (S_LEN * BATCH) + b * S_LEN;

#define STAGE8(DBUF) do { \
    gl_lds16((const unsigned short*)((const char*)kS + kgo0), Sm + (DBUF) * 4096 + wid * 1024); \
    gl_lds16((const unsigned short*)((const char*)vS + vgo0), Sm + 12288 + (DBUF) * 4096 + wid * 1024); \
    gl_lds16((const unsigned short*)((const char*)kS + kgo1), Sm + (DBUF) * 4096 + wid * 1024 + 512); \
    gl_lds16((const unsigned short*)((const char*)vS + vgo1), Sm + 12288 + (DBUF) * 4096 + wid * 1024 + 512); \
    kS += 64 * EMB; vS += 64; } while (0)

    auto pack2 = [](float lo, float hh) -> unsigned {
        unsigned short a  = __builtin_bit_cast(unsigned short, (__bf16)lo);
        unsigned short bb = __builtin_bit_cast(unsigned short, (__bf16)hh);
        return ((unsigned)bb << 16) | a;
    };

    float m_run = 0.f, l_run = 0.f;
    f32x16 oacc0 = {}, oacc1 = {};
    const f32x16 Z16 = {};

    // persistent cross-iteration fragments (previous chunk's P and V)
    bf8 P0 = {}, P1 = {}, P2 = {}, P3 = {};
    bf8 Va0 = {}, Va1 = {}, Va2 = {}, Va3 = {};
    bf8 Vb0 = {}, Vb1 = {}, Vb2 = {}, Vb3 = {};

    STAGE8(0);
    STAGE8(1);

#define ABODY(BUF, DOSTG, LASTW, DOPV) do { \
    if (LASTW) asm volatile("s_waitcnt vmcnt(0)" ::: "memory"); \
    else       asm volatile("s_waitcnt vmcnt(4)" ::: "memory"); \
    __builtin_amdgcn_s_barrier(); \
    if (DOSTG) STAGE8(((BUF) + 2) % 3); \
    bf8 ka0 = *(const bf8*)(ldsc + koA0 + (BUF) * 8192); \
    bf8 ka1 = *(const bf8*)(ldsc + koA1 + (BUF) * 8192); \
    bf8 ka2 = *(const bf8*)(ldsc + koA2 + (BUF) * 8192); \
    bf8 ka3 = *(const bf8*)(ldsc + koA3 + (BUF) * 8192); \
    bf8 kb0 = *(const bf8*)(ldsc + koA0 + (BUF) * 8192 + 4096); \
    bf8 kb1 = *(const bf8*)(ldsc + koA1 + (BUF) * 8192 + 4096); \
    bf8 kb2 = *(const bf8*)(ldsc + koA2 + (BUF) * 8192 + 4096); \
    bf8 kb3 = *(const bf8*)(ldsc + koA3 + (BUF) * 8192 + 4096); \
    bf8 nva0 = *(const bf8*)(ldsc + koA0 + 24576 + (BUF) * 8192); \
    bf8 nva1 = *(const bf8*)(ldsc + koA1 + 24576 + (BUF) * 8192); \
    bf8 nva2 = *(const bf8*)(ldsc + koA2 + 24576 + (BUF) * 8192); \
    bf8 nva3 = *(const bf8*)(ldsc + koA3 + 24576 + (BUF) * 8192); \
    bf8 nvb0 = *(const bf8*)(ldsc + koA0 + 24576 + (BUF) * 8192 + 4096); \
    bf8 nvb1 = *(const bf8*)(ldsc + koA1 + 24576 + (BUF) * 8192 + 4096); \
    bf8 nvb2 = *(const bf8*)(ldsc + koA2 + 24576 + (BUF) * 8192 + 4096); \
    bf8 nvb3 = *(const bf8*)(ldsc + koA3 + 24576 + (BUF) * 8192 + 4096); \
    __builtin_amdgcn_s_setprio(1); \
    f32x16 stA = __builtin_amdgcn_mfma_f32_32x32x16_bf16(ka0, qf[0], Z16, 0, 0, 0); \
    f32x16 stB = __builtin_amdgcn_mfma_f32_32x32x16_bf16(kb0, qf[0], Z16, 0, 0, 0); \
    stA = __builtin_amdgcn_mfma_f32_32x32x16_bf16(ka1, qf[1], stA, 0, 0, 0); \
    stB = __builtin_amdgcn_mfma_f32_32x32x16_bf16(kb1, qf[1], stB, 0, 0, 0); \
    stA = __builtin_amdgcn_mfma_f32_32x32x16_bf16(ka2, qf[2], stA, 0, 0, 0); \
    stB = __builtin_amdgcn_mfma_f32_32x32x16_bf16(kb2, qf[2], stB, 0, 0, 0); \
    stA = __builtin_amdgcn_mfma_f32_32x32x16_bf16(ka3, qf[3], stA, 0, 0, 0); \
    stB = __builtin_amdgcn_mfma_f32_32x32x16_bf16(kb3, qf[3], stB, 0, 0, 0); \
    if (DOPV) { \
        oacc0 = __builtin_amdgcn_mfma_f32_32x32x16_bf16(P0, Va0, oacc0, 0, 0, 0); \
        oacc1 = __builtin_amdgcn_mfma_f32_32x32x16_bf16(P0, Vb0, oacc1, 0, 0, 0); \
        oacc0 = __builtin_amdgcn_mfma_f32_32x32x16_bf16(P1, Va1, oacc0, 0, 0, 0); \
        oacc1 = __builtin_amdgcn_mfma_f32_32x32x16_bf16(P1, Vb1, oacc1, 0, 0, 0); \
        oacc0 = __builtin_amdgcn_mfma_f32_32x32x16_bf16(P2, Va2, oacc0, 0, 0, 0); \
        oacc1 = __builtin_amdgcn_mfma_f32_32x32x16_bf16(P2, Vb2, oacc1, 0, 0, 0); \
        oacc0 = __builtin_amdgcn_mfma_f32_32x32x16_bf16(P3, Va3, oacc0, 0, 0, 0); \
        oacc1 = __builtin_amdgcn_mfma_f32_32x32x16_bf16(P3, Vb3, oacc1, 0, 0, 0); \
    } \
    __builtin_amdgcn_s_setprio(0); \
    float g0 = f3max(f3max(stA[0], stA[1], stA[2]),  f3max(stA[3], stA[4], stA[5]),  f3max(stA[6], stA[7], stA[8])); \
    float g1 = f3max(f3max(stA[9], stA[10], stA[11]), f3max(stA[12], stA[13], stA[14]), fmaxf(stA[15], stB[0])); \
    float g2 = f3max(f3max(stB[1], stB[2], stB[3]),  f3max(stB[4], stB[5], stB[6]),  f3max(stB[7], stB[8], stB[9])); \
    float g3 = f3max(f3max(stB[10], stB[11], stB[12]), f3max(stB[13], stB[14], stB[15]), fmaxf(g0, g1)); \
    float pmax = f3max(g2, g3, g0); \
    pmax = fmaxf(pmax, __shfl_xor(pmax, 32)); \
    if (!__all(pmax - m_run <= 11.54f)) { \
        float mnew = fmaxf(m_run, pmax); \
        float corr = fexp2(m_run - mnew); \
        l_run *= corr; m_run = mnew; \
        if (hi == 0) bl[wid][l31] = corr; \
        asm volatile("s_waitcnt lgkmcnt(0)" ::: "memory"); \
        _Pragma("unroll") for (int r = 0; r < 16; ++r) { \
            float c2 = bl[wid][(r & 3) + 8 * (r >> 2) + 4 * hi]; \
            oacc0[r] *= c2; oacc1[r] *= c2; } \
    } \
    float pA[16], pB[16]; \
    _Pragma("unroll") for (int r = 0; r < 16; ++r) pA[r] = fexp2(stA[r] - m_run); \
    _Pragma("unroll") for (int r = 0; r < 16; ++r) pB[r] = fexp2(stB[r] - m_run); \
    float sA = (((pA[0] + pA[1]) + (pA[2] + pA[3])) + ((pA[4] + pA[5]) + (pA[6] + pA[7]))) \
             + (((pA[8] + pA[9]) + (pA[10] + pA[11])) + ((pA[12] + pA[13]) + (pA[14] + pA[15]))); \
    float sB = (((pB[0] + pB[1]) + (pB[2] + pB[3])) + ((pB[4] + pB[5]) + (pB[6] + pB[7]))) \
             + (((pB[8] + pB[9]) + (pB[10] + pB[11])) + ((pB[12] + pB[13]) + (pB[14] + pB[15]))); \
    float psum = sA + sB; \
    psum += __shfl_xor(psum, 32); \
    l_run += psum; \
    unsigned a0w = pack2(pA[0], pA[1]),  a1w = pack2(pA[2], pA[3]); \
    unsigned a2w = pack2(pA[4], pA[5]),  a3w = pack2(pA[6], pA[7]); \
    unsigned a4w = pack2(pA[8], pA[9]),  a5w = pack2(pA[10], pA[11]); \
    unsigned a6w = pack2(pA[12], pA[13]), a7w = pack2(pA[14], pA[15]); \
    unsigned rA_ = (unsigned)__shfl_xor((int)(hi ? a0w : a2w), 32); \
    unsigned rB_ = (unsigned)__shfl_xor((int)(hi ? a1w : a3w), 32); \
    unsigned rC_ = (unsigned)__shfl_xor((int)(hi ? a4w : a6w), 32); \
    unsigned rD_ = (unsigned)__shfl_xor((int)(hi ? a5w : a7w), 32); \
    uint4 uA0 = hi ? uint4{rA_, rB_, a2w, a3w} : uint4{a0w, a1w, rA_, rB_}; \
    uint4 uA1 = hi ? uint4{rC_, rD_, a6w, a7w} : uint4{a4w, a5w, rC_, rD_}; \
    P0 = __builtin_bit_cast(bf8, uA0); \
    P1 = __builtin_bit_cast(bf8, uA1); \
    unsigned b0w = pack2(pB[0], pB[1]),  b1w = pack2(pB[2], pB[3]); \
    unsigned b2w = pack2(pB[4], pB[5]),  b3w = pack2(pB[6], pB[7]); \
    unsigned b4w = pack2(pB[8], pB[9]),  b5w = pack2(pB[10], pB[11]); \
    unsigned b6w = pack2(pB[12], pB[13]), b7w = pack2(pB[14], pB[15]); \
    unsigned rE_ = (unsigned)__shfl_xor((int)(hi ? b0w : b2w), 32); \
    unsigned rF_ = (unsigned)__shfl_xor((int)(hi ? b1w : b3w), 32); \
    unsigned rG_ = (unsigned)__shfl_xor((int)(hi ? b4w : b6w), 32); \
    unsigned rH_ = (unsigned)__shfl_xor((int)(hi ? b5w : b7w), 32); \
    uint4 uB0 = hi ? uint4{rE_, rF_, b2w, b3w} : uint4{b0w, b1w, rE_, rF_}; \
    uint4 uB1 = hi ? uint4{rG_, rH_, b6w, b7w} : uint4{b4w, b5w, rG_, rH_}; \
    P2 = __builtin_bit_cast(bf8, uB0); \
    P3 = __builtin_bit_cast(bf8, uB1); \
    Va0 = nva0; Va1 = nva1; Va2 = nva2; Va3 = nva3; \
    Vb0 = nvb0; Vb1 = nvb1; Vb2 = nvb2; Vb3 = nvb3; \
    asm volatile("s_waitcnt lgkmcnt(0)" ::: "memory"); \
} while (0)

    // 32 chunks: t=0 (no PV), then t=1..29 staged, t=30,31 unstaged
    ABODY(0, true, false, false);
    ABODY(1, true, false, true);
    ABODY(2, true, false, true);
    for (int t3 = 0; t3 < 9; ++t3) {
        ABODY(0, true, false, true);
        ABODY(1, true, false, true);
        ABODY(2, true, false, true);
    }
    ABODY(0, false, false, true);
    ABODY(1, false, true,  true);

    // tail: PV for the final chunk
    oacc0 = __builtin_amdgcn_mfma_f32_32x32x16_bf16(P0, Va0, oacc0, 0, 0, 0);
    oacc1 = __builtin_amdgcn_mfma_f32_32x32x16_bf16(P0, Vb0, oacc1, 0, 0, 0);
    oacc0 = __builtin_amdgcn_mfma_f32_32x32x16_bf16(P1, Va1, oacc0, 0, 0, 0);
    oacc1 = __builtin_amdgcn_mfma_f32_32x32x16_bf16(P1, Vb1, oacc1, 0, 0, 0);
    oacc0 = __builtin_amdgcn_mfma_f32_32x32x16_bf16(P2, Va2, oacc0, 0, 0, 0);
    oacc1 = __builtin_amdgcn_mfma_f32_32x32x16_bf16(P2, Vb2, oacc1, 0, 0, 0);
    oacc0 = __builtin_amdgcn_mfma_f32_32x32x16_bf16(P3, Va3, oacc0, 0, 0, 0);
    oacc1 = __builtin_amdgcn_mfma_f32_32x32x16_bf16(P3, Vb3, oacc1, 0, 0, 0);

#undef ABODY
#undef STAGE8

    // ---- epilogue: broadcast denominators, normalize, store bf16 ----
    if (hi == 0) bl[wid][l31] = l_run;
    asm volatile("s_waitcnt lgkmcnt(0)" ::: "memory");
#pragma unroll
    for (int r = 0; r < 16; ++r) {
        int q = (r & 3) + 8 * (r >> 2) + 4 * hi;
        float linv = 1.0f / bl[wid][q];
        size_t base = ((size_t)(b * S_LEN + q0 + q)) * EMB + h * HDIM + l31;
        ob[base]      = f2bf(oacc0[r] * linv);
        ob[base + 32] = f2bf(oacc1[r] * linv);
    }
}

// ---------------- final GEMM (out fp32, row remap) ----------------
template<int EPI, typename OutT>
__global__ void __launch_bounds__(256) k_gemm(
    const unsigned short* __restrict__ A,
    const unsigned short* __restrict__ B,
    const float* __restrict__ bias,
    OutT* __restrict__ C,
    int M, int N, int K)
{
    __shared__ __align__(16) unsigned short As[128 * 32];
    __shared__ __align__(16) unsigned short Bs[128 * 32];
    const int tid  = threadIdx.x;
    const int lane = tid & 63;
    const int wid  = tid >> 6;
    const int wm = wid >> 1, wn = wid & 1;
    const int l15 = lane & 15, lh = lane >> 4;
    const int tm0 = blockIdx.y * 128, tn0 = blockIdx.x * 128;

    f32x4 acc[4][4] = {};

    for (int k0 = 0; k0 < K; k0 += 32) {
        __syncthreads();
#pragma unroll
        for (int rnd = 0; rnd < 2; ++rnd) {
            int cbase = wid * 64 + rnd * 256;
            int c = cbase + lane;
            int row = c >> 2, co = (c & 3) * 8;
            gl_lds16(A + (size_t)(tm0 + row) * K + k0 + co, &As[cbase * 8]);
            gl_lds16(B + (size_t)(tn0 + row) * K + k0 + co, &Bs[cbase * 8]);
        }
        __syncthreads();
        bf8 a[4], b[4];
#pragma unroll
        for (int i = 0; i < 4; ++i) {
            a[i] = *(const bf8*)&As[(wm * 64 + i * 16 + l15) * 32 + lh * 8];
            b[i] = *(const bf8*)&Bs[(wn * 64 + i * 16 + l15) * 32 + lh * 8];
        }
#pragma unroll
        for (int i = 0; i < 4; ++i)
#pragma unroll
            for (int j = 0; j < 4; ++j)
                acc[i][j] = __builtin_amdgcn_mfma_f32_16x16x32_bf16(a[i], b[j], acc[i][j], 0, 0, 0);
    }

#pragma unroll
    for (int i = 0; i < 4; ++i) {
        const int rowb = tm0 + wm * 64 + i * 16 + lh * 4;
#pragma unroll
        for (int j = 0; j < 4; ++j) {
            const int col = tn0 + wn * 64 + j * 16 + l15;
#pragma unroll
            for (int r = 0; r < 4; ++r) {
                float v = acc[i][j][r];
                int row = rowb + r;
                if (EPI == 0) {
                    v += bias[col];
                    C[(size_t)row * N + col] = (OutT)f2bf(v);
                } else {
                    v += bias[col];
                    int bb = row >> 11, ss = row & 2047;
                    ((float*)C)[(size_t)(ss * BATCH + bb) * N + col] = v;
                }
            }
        }
    }
}

extern "C" void kernel_launch(void* const* d_in, const int* in_sizes, int n_in,
                              void* d_out, int out_size, void* d_ws, size_t ws_size,
                              hipStream_t stream)
{
    (void)in_sizes; (void)n_in; (void)out_size; (void)ws_size;
    const float* query = (const float*)d_in[0];
    const float* wq = (const float*)d_in[1];
    const float* bq = (const float*)d_in[2];
    const float* wk = (const float*)d_in[3];
    const float* bk = (const float*)d_in[4];
    const float* wv = (const float*)d_in[5];
    const float* bv = (const float*)d_in[6];
    const float* wo = (const float*)d_in[7];
    const float* bo = (const float*)d_in[8];

    // ws layout, 41 MB peak:
    //  [0,1)    cosT/sinT
    //  [1,9)    xb
    //  [9,17)   wqb/wkb/wvb/wob (2 MB each)
    //  [17,25)  qb -> ob (attn writes its own rows after reading them)
    //  [25,33)  kb
    //  [33,41)  vT
    char* ws = (char*)d_ws;
    float*          cosT = (float*)(ws + 0);
    float*          sinT = (float*)(ws + (512 << 10));
    unsigned short* xb   = (unsigned short*)(ws + (1  << 20));
    unsigned short* wqb  = (unsigned short*)(ws + (9  << 20));
    unsigned short* wkb  = (unsigned short*)(ws + (11 << 20));
    unsigned short* wvb  = (unsigned short*)(ws + (13 << 20));
    unsigned short* wob  = (unsigned short*)(ws + (15 << 20));
    unsigned short* qb   = (unsigned short*)(ws + (17 << 20));
    unsigned short* ob   = qb;                                  // time-shared
    unsigned short* kb   = (unsigned short*)(ws + (25 << 20));
    unsigned short* vT   = (unsigned short*)(ws + (33 << 20));

    k_prep<<<8704, 256, 0, stream>>>(query, wq, wk, wv, wo,
                                     cosT, sinT, xb, wqb, wkb, wvb, wob);

    dim3 gq(EMB / 128, (S_LEN * BATCH) / 128, 3);    // (8, 32, 3)
    k_gemmQKV<<<gq, 256, 0, stream>>>(xb, wqb, wkb, wvb, bq, bk, bv,
                                      qb, kb, vT, cosT, sinT);

    k_attn11<<<512, 256, 0, stream>>>(qb, kb, vT, ob);   // flat grid, XCD-swizzled

    dim3 g1(EMB / 128, (S_LEN * BATCH) / 128);       // (8, 32)
    k_gemm<1, float><<<g1, 256, 0, stream>>>(ob, wob, bo, (float*)d_out, 4096, 1024, 1024);
}